// Round 7
// baseline (635.245 us; speedup 1.0000x reference)
//
#include <hip/hip_runtime.h>
#include <hip/hip_bf16.h>
#include <math.h>

#define NB 16
#define SS 2048
#define DQ 128
#define SCALE 0.08838834764831845f       // 1/sqrt(128)
#define EXP2SCALE 0.1275325865719469f    // SCALE * log2(e)

typedef __bf16 bf16x8 __attribute__((ext_vector_type(8)));
typedef unsigned short ushort8_t __attribute__((ext_vector_type(8)));
typedef float floatx4 __attribute__((ext_vector_type(4)));

union FragU { ushort8_t u; bf16x8 b; uint4 i; };

// packed fp32x2 -> bf16x2 (v_cvt_pk_bf16_f32 on gfx950, RNE)
__device__ __forceinline__ unsigned int pk2(float lo, float hi) {
  union { __hip_bfloat162 h; unsigned int u; } cv;
  cv.h = __float22bfloat162_rn(make_float2(lo, hi));
  return cv.u;
}
__device__ __forceinline__ uint4 pack8(float4 a, float4 c) {
  return make_uint4(pk2(a.x, a.y), pk2(a.z, a.w), pk2(c.x, c.y), pk2(c.z, c.w));
}
__device__ __forceinline__ bf16x8 ld_frag(const unsigned short* p) {
  FragU t; t.u = *(const ushort8_t*)p; return t.b;
}
__device__ __forceinline__ floatx4 mfma16(bf16x8 a, bf16x8 b, floatx4 c) {
  return __builtin_amdgcn_mfma_f32_16x16x32_bf16(a, b, c, 0, 0, 0);
}

// LDS-only barrier: waits DS ops, leaves global loads (vmcnt) IN FLIGHT.
__device__ __forceinline__ void bar_lds() {
  asm volatile("s_waitcnt lgkmcnt(0)\n\ts_barrier" ::: "memory");
}

// d_out scratch layout per batch b (each row = DQ floats):
//   rows q0..q0+15 for q0 in {0,64,...}: replicated Linv strips (2048 floats)
//   rows 16..31: colsum accumulator (2048 floats)  [disjoint from strips]
// All overwritten by pass2's final output.

// ---------------------------------------------------------------------------
__global__ void zero_accum(float* __restrict__ O) {
  float* p = O + (size_t)blockIdx.x * SS * DQ + 16 * DQ;
#pragma unroll
  for (int i = 0; i < 8; ++i) p[threadIdx.x + 256 * i] = 0.f;
}

// ---------------------------------------------------------------------------
// Pass 1: partial colsum[b][k] += sum_{q in chunk} exp(masked_score)
// grid (64 ktiles, NB, 4 qchunks) = 4096 blocks, 256 thr, 3 blocks/CU.
// BARRIER-FREE streaming: K A-frags live in registers (loaded once);
// Q B-frags + mask are wave-private, register-prefetched one iter ahead.
// No LDS in the loop -> no sync points, pure vmcnt pipelining.
// ---------------------------------------------------------------------------
__global__ __launch_bounds__(256, 3) void pass1_colsum(
    const float* __restrict__ Q, const float* __restrict__ K,
    const int* __restrict__ M, float* __restrict__ O)
{
  const int k0  = blockIdx.x * 32;
  const int b   = blockIdx.y;
  const int qc  = blockIdx.z;
  const int tid = threadIdx.x;
  const int w = tid >> 6, lane = tid & 63, l15 = lane & 15, quad = lane >> 4;

  __shared__ float red[4][32];

  const float* Qb = Q + (size_t)b * SS * DQ;
  const float* Kb = K + (size_t)b * SS * DQ;
  const int*   Mb = M + (size_t)b * SS * SS;

  // K A-fragments in registers, loaded once: kf[j][d0], k-local = 16j+l15
  FragU kf[2][4];
#pragma unroll
  for (int j = 0; j < 2; ++j) {
    const float* krow = Kb + (size_t)(k0 + 16 * j + l15) * DQ;
#pragma unroll
    for (int d0 = 0; d0 < 4; ++d0) {
      float4 a = *(const float4*)(krow + 32 * d0 + 8 * quad);
      float4 c = *(const float4*)(krow + 32 * d0 + 8 * quad + 4);
      kf[j][d0].i = pack8(a, c);
    }
  }

  const int qlane = 16 * w + l15;      // this lane's q row within a 64-q iter
  const int qbase = qc * 512;

  // prologue: prefetch iter-0 Q row + mask into registers
  float4 qreg[8];
  int4 mv_nxt[2];
  {
    const float* qrow = Qb + (size_t)(qbase + qlane) * DQ;
#pragma unroll
    for (int d0 = 0; d0 < 4; ++d0) {
      qreg[2 * d0]     = *(const float4*)(qrow + 32 * d0 + 8 * quad);
      qreg[2 * d0 + 1] = *(const float4*)(qrow + 32 * d0 + 8 * quad + 4);
    }
    const int* mp = Mb + (size_t)(qbase + qlane) * SS + k0;
    mv_nxt[0] = *(const int4*)(mp + quad * 4);
    mv_nxt[1] = *(const int4*)(mp + 16 + quad * 4);
  }

  float colacc[8];
#pragma unroll
  for (int t = 0; t < 8; ++t) colacc[t] = 0.f;

  for (int qi = 0; qi < 8; ++qi) {
    int4 mv[2] = {mv_nxt[0], mv_nxt[1]};
    FragU qf[4];
#pragma unroll
    for (int d0 = 0; d0 < 4; ++d0)
      qf[d0].i = pack8(qreg[2 * d0], qreg[2 * d0 + 1]);

    if (qi < 7) {  // prefetch next iter (stays in flight through compute)
      const int qn = qbase + (qi + 1) * 64 + qlane;
      const float* qrow = Qb + (size_t)qn * DQ;
#pragma unroll
      for (int d0 = 0; d0 < 4; ++d0) {
        qreg[2 * d0]     = *(const float4*)(qrow + 32 * d0 + 8 * quad);
        qreg[2 * d0 + 1] = *(const float4*)(qrow + 32 * d0 + 8 * quad + 4);
      }
      const int* mp = Mb + (size_t)qn * SS + k0;
      mv_nxt[0] = *(const int4*)(mp + quad * 4);
      mv_nxt[1] = *(const int4*)(mp + 16 + quad * 4);
    }

    floatx4 acc[2];
    acc[0] = (floatx4){0.f, 0.f, 0.f, 0.f};
    acc[1] = (floatx4){0.f, 0.f, 0.f, 0.f};
#pragma unroll
    for (int d0 = 0; d0 < 4; ++d0) {
#pragma unroll
      for (int j = 0; j < 2; ++j)
        acc[j] = mfma16(kf[j][d0].b, qf[d0].b, acc[j]);
    }
    // epilogue: C row = k_local = 16j+quad*4+r, col = q = qlane
#pragma unroll
    for (int j = 0; j < 2; ++j) {
      int mm[4] = {mv[j].x, mv[j].y, mv[j].z, mv[j].w};
#pragma unroll
      for (int r = 0; r < 4; ++r) {
        // exp(score) = exp2(acc*EXP2SCALE); masked -> exp(1e-9) ~= exp2(0)
        float s = mm[r] ? 0.f : acc[j][r] * EXP2SCALE;
        colacc[j * 4 + r] += exp2f(s);
      }
    }
  }

  // reduce over the 16 q-lanes (l15 dim; xor masks stay within each quad)
#pragma unroll
  for (int t = 0; t < 8; ++t) {
    colacc[t] += __shfl_xor(colacc[t], 1, 64);
    colacc[t] += __shfl_xor(colacc[t], 2, 64);
    colacc[t] += __shfl_xor(colacc[t], 4, 64);
    colacc[t] += __shfl_xor(colacc[t], 8, 64);
  }
  if (l15 == 0) {
#pragma unroll
    for (int j = 0; j < 2; ++j)
#pragma unroll
      for (int r = 0; r < 4; ++r)
        red[w][16 * j + quad * 4 + r] = colacc[j * 4 + r];
  }
  __syncthreads();
  if (tid < 32) {
    float s = red[0][tid] + red[1][tid] + red[2][tid] + red[3][tid];
    atomicAdd(O + (size_t)b * SS * DQ + 16 * DQ + k0 + tid, s);
  }
}

// ---------------------------------------------------------------------------
// Combine: inv = 1/colsum; write replicated strips. grid (NB, 8), 256 thr.
// ---------------------------------------------------------------------------
__global__ void combine_linv(float* __restrict__ O) {
  const int b  = blockIdx.x;
  const int jb = blockIdx.y * 4;
  float* Ob = O + (size_t)b * SS * DQ;
#pragma unroll
  for (int it = 0; it < 8; ++it) {
    int k = threadIdx.x + 256 * it;
    float inv = 1.0f / Ob[16 * DQ + k];
#pragma unroll
    for (int j = 0; j < 4; ++j)
      Ob[(size_t)(64 * (jb + j)) * DQ + k] = inv;
  }
}

// ---------------------------------------------------------------------------
// Pass 2: O[q][d] = sum_k exp(masked_score)*Linv[k]*V[k][d]
// grid (32, NB) = 512 blocks (2/CU), 256 thr. Q in registers; Es rows
// wave-private (no barrier before PV). K/V/mask register-prefetched one
// k-tile ahead; LDS-only barriers; packed bf16 conversions throughout.
// ---------------------------------------------------------------------------
__global__ __launch_bounds__(256, 2) void pass2_out(
    const float* __restrict__ Q, const float* __restrict__ K,
    const float* __restrict__ V, const int* __restrict__ M,
    float* __restrict__ O)
{
  const int b = blockIdx.y, q0 = blockIdx.x * 64;
  const int tid = threadIdx.x;
  const int w = tid >> 6, lane = tid & 63, l15 = lane & 15, quad = lane >> 4;

  __shared__ unsigned short Kbf[64][136];  // 17.4 KB
  __shared__ unsigned short Es[64][72];    //  9.2 KB  [q][k], wave-private rows
  __shared__ unsigned short Wt[128][72];   // 18.4 KB  [d][k^swz]
  __shared__ float Li[SS];                 //  8.0 KB

  const float* Qb = Q + (size_t)b * SS * DQ;
  const float* Kb = K + (size_t)b * SS * DQ;
  const float* Vb = V + (size_t)b * SS * DQ;
  const int*   Mb = M + (size_t)b * SS * SS;

  const int srow = tid >> 5;
  const int sc4  = (tid & 31) * 4;

  // preload replicated Linv strip from own territory (before any O write)
  {
    const float* src = O + ((size_t)b * SS + q0) * DQ;
#pragma unroll
    for (int r = 0; r < 2; ++r) {
      int idx = (tid + r * 256) * 4;
      *(float4*)&Li[idx] = *(const float4*)(src + idx);
    }
  }
  // Q fragments in registers: this lane's q row, 4 fragments over d
  FragU qf[4];
  {
    const float* qrow = Qb + (size_t)(q0 + 16 * w + l15) * DQ;
#pragma unroll
    for (int i = 0; i < 4; ++i) {
      float4 a = *(const float4*)(qrow + 32 * i + quad * 8);
      float4 c = *(const float4*)(qrow + 32 * i + quad * 8 + 4);
      qf[i].i = pack8(a, c);
    }
  }

  floatx4 accO[8];
#pragma unroll
  for (int j = 0; j < 8; ++j) accO[j] = (floatx4){0.f, 0.f, 0.f, 0.f};

  const int* mrow = Mb + (size_t)(q0 + 16 * w + l15) * SS;  // this lane's q-row

  // prologue: prefetch k-tile 0 (K rows, V row-pairs, mask) into registers
  float4 kreg[8], vreg[8];
  int4 mv_nxt[4];
  const int vk2 = (tid >> 5) * 2;   // V row-pair base for this thread
  {
#pragma unroll
    for (int r = 0; r < 8; ++r)
      kreg[r] = *(const float4*)(Kb + (size_t)(srow + r * 8) * DQ + sc4);
#pragma unroll
    for (int r = 0; r < 4; ++r) {
      int k2 = vk2 + r * 16;
      vreg[2 * r]     = *(const float4*)(Vb + (size_t)(k2)     * DQ + sc4);
      vreg[2 * r + 1] = *(const float4*)(Vb + (size_t)(k2 + 1) * DQ + sc4);
    }
#pragma unroll
    for (int j = 0; j < 4; ++j)
      mv_nxt[j] = *(const int4*)(mrow + 16 * j + quad * 4);
  }

  for (int k0 = 0; k0 < SS; k0 += 64) {
    bar_lds();  // prev iter's Kbf/Wt readers done; Li/initial ds_writes drained
    int4 mv[4] = {mv_nxt[0], mv_nxt[1], mv_nxt[2], mv_nxt[3]};

    // store prefetched K -> Kbf (packed bf16)
#pragma unroll
    for (int r = 0; r < 8; ++r) {
      float4 v = kreg[r];
      *(uint2*)&Kbf[srow + r * 8][sc4] = make_uint2(pk2(v.x, v.y), pk2(v.z, v.w));
    }
    // store prefetched V -> Wt (transposed, xor-swizzled, packed pairs)
#pragma unroll
    for (int r = 0; r < 4; ++r) {
      int k2 = vk2 + r * 16;
      float fa[4] = {vreg[2*r].x, vreg[2*r].y, vreg[2*r].z, vreg[2*r].w};
      float fb[4] = {vreg[2*r+1].x, vreg[2*r+1].y, vreg[2*r+1].z, vreg[2*r+1].w};
#pragma unroll
      for (int i = 0; i < 4; ++i) {
        int d  = sc4 + i;
        int kk = k2 ^ ((((unsigned)d >> 2) & 7) << 3);   // xor on k-bits 3..5
        *(unsigned int*)&Wt[d][kk] = pk2(fa[i], fb[i]);
      }
    }
    bar_lds();  // LDS ready; the prefetch below stays in flight across iters

    if (k0 + 64 < SS) {
      const int kn = k0 + 64;
#pragma unroll
      for (int r = 0; r < 8; ++r)
        kreg[r] = *(const float4*)(Kb + (size_t)(kn + srow + r * 8) * DQ + sc4);
#pragma unroll
      for (int r = 0; r < 4; ++r) {
        int k2 = vk2 + r * 16;
        vreg[2 * r]     = *(const float4*)(Vb + (size_t)(kn + k2)     * DQ + sc4);
        vreg[2 * r + 1] = *(const float4*)(Vb + (size_t)(kn + k2 + 1) * DQ + sc4);
      }
#pragma unroll
      for (int j = 0; j < 4; ++j)
        mv_nxt[j] = *(const int4*)(mrow + kn + 16 * j + quad * 4);
    }

    // QK: C row = k_local = 16j+quad*4+r, col = q = q0+16w+l15
    floatx4 acc[4];
#pragma unroll
    for (int j = 0; j < 4; ++j) acc[j] = (floatx4){0.f, 0.f, 0.f, 0.f};
#pragma unroll
    for (int i = 0; i < 4; ++i) {
      bf16x8 bq = qf[i].b;
#pragma unroll
      for (int j = 0; j < 4; ++j) {
        bf16x8 ak = ld_frag(&Kbf[16 * j + l15][32 * i + quad * 8]);
        acc[j] = mfma16(ak, bq, acc[j]);
      }
    }
    // epilogue: mask+exp2, fold Linv, write Es (own wave's rows only)
#pragma unroll
    for (int j = 0; j < 4; ++j) {
      float4 liv = *(const float4*)&Li[k0 + 16 * j + quad * 4];
      float lv[4] = {liv.x, liv.y, liv.z, liv.w};
      int mm[4] = {mv[j].x, mv[j].y, mv[j].z, mv[j].w};
      float ev[4];
#pragma unroll
      for (int r = 0; r < 4; ++r) {
        float s = mm[r] ? 0.f : acc[j][r] * EXP2SCALE;
        ev[r] = exp2f(s) * lv[r];
      }
      *(uint2*)&Es[16 * w + l15][16 * j + quad * 4] =
          make_uint2(pk2(ev[0], ev[1]), pk2(ev[2], ev[3]));
    }
    // PV (no barrier: Es rows written & read by the same wave; lgkm ordering)
#pragma unroll
    for (int c = 0; c < 2; ++c) {
      bf16x8 be = ld_frag(&Es[16 * w + l15][32 * c + quad * 8]);
#pragma unroll
      for (int j = 0; j < 8; ++j) {
        int d  = 16 * j + l15;
        int kk = (32 * c + quad * 8) ^ ((((unsigned)d >> 2) & 7) << 3);
        bf16x8 aw = ld_frag(&Wt[d][kk]);
        accO[j] = mfma16(aw, be, accO[j]);
      }
    }
  }

  // write O: C row = d = 16j+quad*4+r, col = q = q0+16w+l15 -> float4 stores
#pragma unroll
  for (int j = 0; j < 8; ++j) {
    float* op = O + ((size_t)b * SS + q0 + 16 * w + l15) * DQ + 16 * j + quad * 4;
    *(float4*)op = make_float4(accO[j][0], accO[j][1], accO[j][2], accO[j][3]);
  }
}

// ---------------------------------------------------------------------------
extern "C" void kernel_launch(void* const* d_in, const int* in_sizes, int n_in,
                              void* d_out, int out_size, void* d_ws, size_t ws_size,
                              hipStream_t stream) {
  const float* Q = (const float*)d_in[0];
  const float* K = (const float*)d_in[1];
  const float* V = (const float*)d_in[2];
  const int*   M = (const int*)d_in[3];
  float* O = (float*)d_out;
  (void)d_ws; (void)ws_size;   // d_ws unused (R0 post-mortem; scheme verified R2-R6)

  zero_accum<<<dim3(NB), 256, 0, stream>>>(O);
  pass1_colsum<<<dim3(64, NB, 4), 256, 0, stream>>>(Q, K, M, O);
  combine_linv<<<dim3(NB, 8), 256, 0, stream>>>(O);
  pass2_out<<<dim3(32, NB), 256, 0, stream>>>(Q, K, V, M, O);
}